// Round 9
// baseline (559.689 us; speedup 1.0000x reference)
//
#include <hip/hip_runtime.h>

#define NT 64
#define SEQ 1024
#define BATCH 512

typedef _Float16 h2 __attribute__((ext_vector_type(2)));

__device__ __forceinline__ float rlf(float v, int lane) {
  return __int_as_float(__builtin_amdgcn_readlane(__float_as_int(v), lane));
}
__device__ __forceinline__ float bsum(float v) {  // 64-lane butterfly sum
  #pragma unroll
  for (int m = 32; m; m >>= 1) v += __shfl_xor(v, m);
  return v;
}
__device__ __forceinline__ float dot2(h2 a, h2 b, float c) {
#if __has_builtin(__builtin_amdgcn_fdot2)
  return __builtin_amdgcn_fdot2(a, b, c, false);
#else
  return fmaf((float)a[0], (float)b[0], fmaf((float)a[1], (float)b[1], c));
#endif
}

// Full-coverage DPP mov (row_mask=0xF, bank_mask=0xF, bound_ctrl=1).
template <int CTRL>
__device__ __forceinline__ unsigned dmov(unsigned v) {
  return (unsigned)__builtin_amdgcn_update_dpp(0, (int)v, CTRL, 0xF, 0xF, true);
}
#define DPP_SWAP1 0xB1   // quad_perm [1,0,3,2]
#define DPP_SWAP2 0x4E   // quad_perm [2,3,0,1]
#define DPP_ROR4  0x124  // row_ror:4
#define DPP_ROR8  0x128  // row_ror:8

__device__ __forceinline__ unsigned h2u(h2 v) { return __builtin_bit_cast(unsigned, v); }
__device__ __forceinline__ h2 u2h(unsigned v) { return __builtin_bit_cast(h2, v); }

#if __has_builtin(__builtin_amdgcn_permlane16_swap) && \
    __has_builtin(__builtin_amdgcn_permlane32_swap)
#define HAVE_PLSWAP 1
#else
#define HAVE_PLSWAP 0
#endif

__device__ __forceinline__ float xchg16(float x, bool use0) {
#if HAVE_PLSWAP
  const unsigned xb = __float_as_uint(x);
  auto r = __builtin_amdgcn_permlane16_swap(xb, xb, false, false);
  return __uint_as_float(use0 ? r[0] : r[1]);
#else
  return __shfl_xor(x, 16);
#endif
}
__device__ __forceinline__ float xchg32(float x, bool use0) {
#if HAVE_PLSWAP
  const unsigned xb = __float_as_uint(x);
  auto r = __builtin_amdgcn_permlane32_swap(xb, xb, false, false);
  return __uint_as_float(use0 ? r[0] : r[1]);
#else
  return __shfl_xor(x, 32);
#endif
}

#define SB __builtin_amdgcn_sched_barrier(0)

// TWO batches per wave with FORCED fine-grained interleave. r7 proved in-order
// issue makes sequential dual chains exactly additive (556 = 2x232); this
// version alternates chain A/B at ~phase granularity and pins each phase pair
// with sched_barrier(0) so the emitted order keeps the alternation: chain B's
// issue fills chain A's dependency stalls. Per-chain math is bit-identical to
// the r3/r6/r7-verified path (absmax 0.0): f16 state, DPP all-gather, 4 column
// dots, permlane-swap reduce, 1-step-stale uniform renorm, exq one ahead.
__global__ __launch_bounds__(64, 1) void crf_fwd(
    const float* __restrict__ em,      // [B,S,T]
    const float* __restrict__ startT,  // [T]
    const float* __restrict__ endT,    // [T]
    const float* __restrict__ trans,   // [T,T]
    const int*   __restrict__ tags,    // [B,S] int32
    float* __restrict__ ws)            // [B] per-batch losses
{
  const int bA = blockIdx.x;
  const int bB = blockIdx.x + BATCH / 2;
  const int j = threadIdx.x;  // 0..63

  __shared__ float sT[NT * NT];  // raw transitions (score gather + eth setup)
  for (int i = j; i < NT * NT; i += NT) sT[i] = trans[i];
  __syncthreads();  // once

  // ---- detect which swap output holds the partner value, per lane ----
  bool use0_16 = false, use0_32 = false;
#if HAVE_PLSWAP
  {
    const unsigned jb = (unsigned)j;
    auto a = __builtin_amdgcn_permlane16_swap(jb, jb, false, false);
    use0_16 = (a[0] == (jb ^ 16u));
    auto c = __builtin_amdgcn_permlane32_swap(jb, jb, false, false);
    use0_32 = (c[0] == (jb ^ 32u));
  }
#endif

  // ---- mirror the data all-gather network on packed lane indices ----
  unsigned I[8];
  {
    unsigned tJ = dmov<DPP_SWAP1>((unsigned)j);
    I[0] = (unsigned)j | (tJ << 16);
    I[1] = dmov<DPP_SWAP2>(I[0]);
    I[2] = dmov<DPP_ROR4>(I[0]);
    I[3] = dmov<DPP_ROR4>(I[1]);
    I[4] = dmov<DPP_ROR8>(I[0]);
    I[5] = dmov<DPP_ROR8>(I[1]);
    I[6] = dmov<DPP_ROR8>(I[2]);
    I[7] = dmov<DPP_ROR8>(I[3]);
  }

  // eth[k][r] = exp(T[src][col_k])/64 (f16), col_k = j ^ (k<<4), src from I[r].
  h2 eth[4][8];
  #pragma unroll
  for (int k = 0; k < 4; ++k) {
    const int col = j ^ (k << 4);
    #pragma unroll
    for (int r = 0; r < 8; ++r) {
      const int lo = (int)(I[r] & 0xFFFFu), hi = (int)(I[r] >> 16);
      h2 e;
      e[0] = (_Float16)(__expf(sT[lo * NT + col]) * 0.015625f);
      e[1] = (_Float16)(__expf(sT[hi * NT + col]) * 0.015625f);
      eth[k][r] = e;
    }
  }

  const float* embA = em + (size_t)bA * SEQ * NT;
  const float* embB = em + (size_t)bB * SEQ * NT;
  const int*   tgbA = tags + (size_t)bA * SEQ;
  const int*   tgbB = tags + (size_t)bB * SEQ;

  const float stv = startT[j];

  const float alpha0A = stv + embA[j];
  const float c0A = rlf(alpha0A, 0);
  float nbA = __expf(alpha0A - c0A);
  const float alpha0B = stv + embB[j];
  const float c0B = rlf(alpha0B, 0);
  float nbB = __expf(alpha0B - c0B);

  float CrnA = 0.0f, rrA = 1.0f, lgrrA = 0.0f;
  float CrnB = 0.0f, rrB = 1.0f, lgrrB = 0.0f;

  // ---- score bookkeeping (off the serial chain; r7-verified) ----
  int tagvA = tgbA[j];
  const int tag0A = __builtin_amdgcn_readlane(tagvA, 0);
  const float sc0A = rlf(stv, tag0A);
  float scpA = 0.0f;
  {
    int ptag = __shfl_up(tagvA, 1);
    if (j > 0) scpA += sT[ptag * NT + tagvA];
    scpA += embA[j * NT + tagvA];
  }
  int carryA = __builtin_amdgcn_readlane(tagvA, 63);

  int tagvB = tgbB[j];
  const int tag0B = __builtin_amdgcn_readlane(tagvB, 0);
  const float sc0B = rlf(stv, tag0B);
  float scpB = 0.0f;
  {
    int ptag = __shfl_up(tagvB, 1);
    if (j > 0) scpB += sT[ptag * NT + tagvB];
    scpB += embB[j * NT + tagvB];
  }
  int carryB = __builtin_amdgcn_readlane(tagvB, 63);

  // embuf[s & 7] holds em row s; preload rows 1..8
  float embufA[8], embufB[8];
  #pragma unroll
  for (int k = 1; k <= 8; ++k) embufA[k & 7] = embA[k * NT + j];
  #pragma unroll
  for (int k = 1; k <= 8; ++k) embufB[k & 7] = embB[k * NT + j];

  float exqA = __expf(embufA[1] - 0.5f);
  float exqB = __expf(embufB[1] - 0.5f);

  #define COLSUMG(P, K, OUT) do {                     \
    float _a = dot2(u2h(P##0), eth[K][0], 0.0f);      \
    _a = dot2(u2h(P##1), eth[K][1], _a);              \
    _a = dot2(u2h(P##2), eth[K][2], _a);              \
    _a = dot2(u2h(P##3), eth[K][3], _a);              \
    float _c = dot2(u2h(P##4), eth[K][4], 0.0f);      \
    _c = dot2(u2h(P##5), eth[K][5], _c);              \
    _c = dot2(u2h(P##6), eth[K][6], _c);              \
    _c = dot2(u2h(P##7), eth[K][7], _c);              \
    OUT = _a + _c;                                    \
  } while (0)

  // One INTERLEAVED step-pair (chains A and B), phase-pinned with SB.
  #define STEP2(s, slot) do {                                                \
    /* R0: prefetch + exp pipeline + multipliers, both chains */             \
    const float exA_ = exqA, exB_ = exqB;                                    \
    int spre_ = (s) + 8;                                                     \
    if (spre_ > SEQ - 1) spre_ = SEQ - 1;                                    \
    const float emnA_ = embufA[((s) + 1) & 7];                               \
    const float emnB_ = embufB[((s) + 1) & 7];                               \
    embufA[slot] = embA[(size_t)spre_ * NT + j];                             \
    embufB[slot] = embB[(size_t)spre_ * NT + j];                             \
    exqA = __expf(emnA_ - 0.5f);                                             \
    exqB = __expf(emnB_ - 0.5f);                                             \
    const float mmA_ = exA_ * rrA;                                           \
    CrnA -= lgrrA;                                                           \
    const float mmB_ = exB_ * rrB;                                           \
    CrnB -= lgrrB;                                                           \
    SB;                                                                      \
    /* R1: f16 pack of state, both chains */                                 \
    const float tvA_ =                                                       \
        __uint_as_float(dmov<DPP_SWAP1>(__float_as_uint(nbA)));              \
    const float tvB_ =                                                       \
        __uint_as_float(dmov<DPP_SWAP1>(__float_as_uint(nbB)));              \
    h2 prA_;                                                                 \
    prA_[0] = (_Float16)nbA;                                                 \
    prA_[1] = (_Float16)tvA_;                                                \
    h2 prB_;                                                                 \
    prB_[0] = (_Float16)nbB;                                                 \
    prB_[1] = (_Float16)tvB_;                                                \
    const unsigned GA0 = h2u(prA_);                                          \
    const unsigned GB0 = h2u(prB_);                                          \
    SB;                                                                      \
    /* R2: DPP fan-out, both chains */                                       \
    const unsigned GA1 = dmov<DPP_SWAP2>(GA0);                               \
    const unsigned GB1 = dmov<DPP_SWAP2>(GB0);                               \
    const unsigned GA2 = dmov<DPP_ROR4>(GA0);                                \
    const unsigned GB2 = dmov<DPP_ROR4>(GB0);                                \
    const unsigned GA3 = dmov<DPP_ROR4>(GA1);                                \
    const unsigned GB3 = dmov<DPP_ROR4>(GB1);                                \
    const unsigned GA4 = dmov<DPP_ROR8>(GA0);                                \
    const unsigned GB4 = dmov<DPP_ROR8>(GB0);                                \
    const unsigned GA5 = dmov<DPP_ROR8>(GA1);                                \
    const unsigned GB5 = dmov<DPP_ROR8>(GB1);                                \
    const unsigned GA6 = dmov<DPP_ROR8>(GA2);                                \
    const unsigned GB6 = dmov<DPP_ROR8>(GB2);                                \
    const unsigned GA7 = dmov<DPP_ROR8>(GA3);                                \
    const unsigned GB7 = dmov<DPP_ROR8>(GB3);                                \
    SB;                                                                      \
    float p0A_, p1A_, p2A_, p3A_, p0B_, p1B_, p2B_, p3B_;                    \
    /* R3/R4: cols j^16, j^48 */                                             \
    COLSUMG(GA, 1, p1A_);                                                    \
    COLSUMG(GB, 1, p1B_);                                                    \
    SB;                                                                      \
    COLSUMG(GA, 3, p3A_);                                                    \
    COLSUMG(GB, 3, p3B_);                                                    \
    SB;                                                                      \
    /* R5: cross-row exchanges */                                            \
    const float r1A_ = xchg16(p1A_, use0_16);                                \
    const float r1B_ = xchg16(p1B_, use0_16);                                \
    const float r3A_ = xchg16(p3A_, use0_16);                                \
    const float r3B_ = xchg16(p3B_, use0_16);                                \
    SB;                                                                      \
    /* R6/R7: cols j, j^32 */                                                \
    COLSUMG(GA, 0, p0A_);                                                    \
    COLSUMG(GB, 0, p0B_);                                                    \
    SB;                                                                      \
    COLSUMG(GA, 2, p2A_);                                                    \
    COLSUMG(GB, 2, p2B_);                                                    \
    SB;                                                                      \
    /* R8: reduce finish + state update */                                   \
    p0A_ += r1A_;                                                            \
    p2A_ += r3A_;                                                            \
    p0B_ += r1B_;                                                            \
    p2B_ += r3B_;                                                            \
    const float r2A_ = xchg32(p2A_, use0_32);                                \
    const float r2B_ = xchg32(p2B_, use0_32);                                \
    p0A_ += r2A_;                                                            \
    p0B_ += r2B_;                                                            \
    nbA = p0A_ * mmA_;                                                       \
    nbB = p0B_ * mmB_;                                                       \
    SB;                                                                      \
    /* R9: next renorm (has a full step of slack) */                         \
    const float rvA_ = rlf(nbA, 0);                                          \
    const float rvB_ = rlf(nbB, 0);                                          \
    rrA = __builtin_amdgcn_rcpf(rvA_);                                       \
    rrB = __builtin_amdgcn_rcpf(rvB_);                                       \
    lgrrA = __logf(rrA);                                                     \
    lgrrB = __logf(rrB);                                                     \
  } while (0)

  // block 0: steps 1..63
  #pragma unroll 8
  for (int r = 1; r < NT; ++r) STEP2(r, r & 7);

  for (int tb = 1; tb < SEQ / NT; ++tb) {
    const int base = tb * NT;
    tagvA = tgbA[base + j];
    {
      int ptag = __shfl_up(tagvA, 1);
      if (j == 0) ptag = carryA;
      scpA += sT[ptag * NT + tagvA];
      scpA += embA[(size_t)(base + j) * NT + tagvA];
    }
    carryA = __builtin_amdgcn_readlane(tagvA, 63);

    tagvB = tgbB[base + j];
    {
      int ptag = __shfl_up(tagvB, 1);
      if (j == 0) ptag = carryB;
      scpB += sT[ptag * NT + tagvB];
      scpB += embB[(size_t)(base + j) * NT + tagvB];
    }
    carryB = __builtin_amdgcn_readlane(tagvB, 63);

    #pragma unroll 8
    for (int r = 0; r < NT; ++r) STEP2(base + r, r & 7);
  }

  // ---- epilogue ----
  const float endv = endT[j];
  const float Cbase = (float)(SEQ - 1) * (0.5f + 4.1588830833596715f);
  {
    const float x = nbA * __expf(endv);
    const float tot = bsum(x);
    const float logz = c0A + Cbase + CrnA + __logf(tot);
    const float sctot = bsum(scpA);
    const float score = sc0A + sctot + rlf(endv, carryA);
    if (j == 0) ws[bA] = logz - score;
  }
  {
    const float x = nbB * __expf(endv);
    const float tot = bsum(x);
    const float logz = c0B + Cbase + CrnB + __logf(tot);
    const float sctot = bsum(scpB);
    const float score = sc0B + sctot + rlf(endv, carryB);
    if (j == 0) ws[bB] = logz - score;
  }
}

__global__ __launch_bounds__(64) void reduce_loss(const float* __restrict__ ws,
                                                  float* __restrict__ out) {
  const int t = threadIdx.x;
  float v = 0.f;
  #pragma unroll
  for (int k = 0; k < BATCH / 64; ++k) v += ws[k * 64 + t];
  const float tot = bsum(v);
  if (t == 0) out[0] = tot;
}

extern "C" void kernel_launch(void* const* d_in, const int* in_sizes, int n_in,
                              void* d_out, int out_size, void* d_ws, size_t ws_size,
                              hipStream_t stream) {
  const float* em    = (const float*)d_in[0];
  const float* st    = (const float*)d_in[1];
  const float* en    = (const float*)d_in[2];
  const float* tr    = (const float*)d_in[3];
  const int*   tags  = (const int*)d_in[4];
  // d_in[5] is mask: all-ones by construction -> ignored.

  float* ws  = (float*)d_ws;
  float* out = (float*)d_out;

  crf_fwd<<<BATCH / 2, 64, 0, stream>>>(em, st, en, tr, tags, ws);
  reduce_loss<<<1, 64, 0, stream>>>(ws, out);
}

// Round 11
// 396.399 us; speedup vs baseline: 1.4119x; 1.4119x over previous
//
#include <hip/hip_runtime.h>

#define NT 64
#define SEQ 1024
#define BATCH 512

__device__ __forceinline__ float rlf(float v, int lane) {
  return __int_as_float(__builtin_amdgcn_readlane(__float_as_int(v), lane));
}
__device__ __forceinline__ float bsum(float v) {  // 64-lane butterfly sum
  #pragma unroll
  for (int m = 32; m; m >>= 1) v += __shfl_xor(v, m);
  return v;
}

// Full-coverage DPP mov (row_mask=0xF, bank_mask=0xF, bound_ctrl=1).
template <int CTRL>
__device__ __forceinline__ unsigned dmov(unsigned v) {
  return (unsigned)__builtin_amdgcn_update_dpp(0, (int)v, CTRL, 0xF, 0xF, true);
}
#define DPP_ROR(i) (0x120 + (i))  // row_ror:i, rotates within each 16-lane row

#if __has_builtin(__builtin_amdgcn_permlane16_swap) && \
    __has_builtin(__builtin_amdgcn_permlane32_swap)
#define HAVE_PLSWAP 1
#else
#define HAVE_PLSWAP 0
#endif

__device__ __forceinline__ float xchg16(float x, bool use0) {
#if HAVE_PLSWAP
  const unsigned xb = __float_as_uint(x);
  auto r = __builtin_amdgcn_permlane16_swap(xb, xb, false, false);
  return __uint_as_float(use0 ? r[0] : r[1]);
#else
  return __shfl_xor(x, 16);
#endif
}
__device__ __forceinline__ float xchg32(float x, bool use0) {
#if HAVE_PLSWAP
  const unsigned xb = __float_as_uint(x);
  auto r = __builtin_amdgcn_permlane32_swap(xb, xb, false, false);
  return __uint_as_float(use0 ? r[0] : r[1]);
#else
  return __shfl_xor(x, 32);
#endif
}

// One wave per batch (r6/r8-verified structure). r9's counter decomposition
// showed ~176 issued instrs/step -- consistent with the f16 dot2 path lowering
// to cvt+fma. This version keeps the state in f32 and FUSES the row-of-16
// gather into the MACs: term i of column k is fmaf(row_ror_i(w), eth[k][i], p)
// -- 15 DPP movs + 64 v_fmac_f32 core, no f16 pack, no gather registers.
// eth indices self-calibrate by pushing lane ids through the same ror network.
// Renorm (1-step stale uniform), exq pipeline, score path: identical to the
// verified r6 path (absmax 0.0).
__global__ __launch_bounds__(64, 1) void crf_fwd(
    const float* __restrict__ em,      // [B,S,T]
    const float* __restrict__ startT,  // [T]
    const float* __restrict__ endT,    // [T]
    const float* __restrict__ trans,   // [T,T]
    const int*   __restrict__ tags,    // [B,S] int32
    float* __restrict__ ws)            // [B] per-batch losses
{
  const int b = blockIdx.x;
  const int j = threadIdx.x;  // 0..63

  __shared__ float sT[NT * NT];  // raw transitions (score gather + eth setup)
  for (int i = j; i < NT * NT; i += NT) sT[i] = trans[i];
  __syncthreads();  // once

  // ---- detect which swap output holds the partner value, per lane ----
  bool use0_16 = false, use0_32 = false;
#if HAVE_PLSWAP
  {
    const unsigned jb = (unsigned)j;
    auto a = __builtin_amdgcn_permlane16_swap(jb, jb, false, false);
    use0_16 = (a[0] == (jb ^ 16u));
    auto c = __builtin_amdgcn_permlane32_swap(jb, jb, false, false);
    use0_32 = (c[0] == (jb ^ 32u));
  }
#endif

  // ---- self-calibrate the ror gather network on lane indices ----
  // idxs[i] = source lane whose w arrives at this lane under row_ror:i.
  unsigned idxs[16];
  idxs[0] = (unsigned)j;
  #define MKIDX(i) idxs[i] = dmov<DPP_ROR(i)>((unsigned)j)
  MKIDX(1);  MKIDX(2);  MKIDX(3);  MKIDX(4);  MKIDX(5);
  MKIDX(6);  MKIDX(7);  MKIDX(8);  MKIDX(9);  MKIDX(10);
  MKIDX(11); MKIDX(12); MKIDX(13); MKIDX(14); MKIDX(15);
  #undef MKIDX

  // eth[k][i] = exp(T[idxs[i]][col_k])/64 (f32), col_k = j ^ (k<<4).
  float eth[4][16];
  #pragma unroll
  for (int k = 0; k < 4; ++k) {
    const int col = j ^ (k << 4);
    #pragma unroll
    for (int i = 0; i < 16; ++i)
      eth[k][i] = __expf(sT[(int)idxs[i] * NT + col]) * 0.015625f;
  }

  const float* emb = em + (size_t)b * SEQ * NT;
  const int*   tgb = tags + (size_t)b * SEQ;

  const float stv = startT[j];
  const float alpha0 = stv + emb[j];
  const float c0 = rlf(alpha0, 0);
  float nb = __expf(alpha0 - c0);  // w_0, lane0 == 1

  float Crn = 0.0f;    // accumulated -log(rr) for APPLIED folds (uniform)
  float rr = 1.0f;     // renorm factor pending application (1-step stale)
  float lgrr = 0.0f;   // __logf(rr) of the pending factor

  // ---- score bookkeeping (off the serial chain; r6-verified) ----
  int tagv = tgb[j];  // lane r holds tag_{base+r}
  const int tag0 = __builtin_amdgcn_readlane(tagv, 0);
  const float sc0 = rlf(stv, tag0);  // start_transitions[tag0]

  float scp = 0.0f;  // per-lane score partial: em gathers + transition gathers
  {
    int ptag = __shfl_up(tagv, 1);
    if (j > 0) scp += sT[ptag * NT + tagv];   // trans[tag_{s-1}][tag_s], s=j
    scp += emb[j * NT + tagv];                // em[s=j][tag_j] (incl. s=0)
  }
  int carry = __builtin_amdgcn_readlane(tagv, 63);

  // embuf[s & 7] holds em row s; preload rows 1..8
  float embuf[8];
  #pragma unroll
  for (int k = 1; k <= 8; ++k) embuf[k & 7] = emb[k * NT + j];

  float exq = __expf(embuf[1] - 0.5f);  // exp(em_1 - 0.5), for step 1

  // term i (i>=1): one DPP mov feeding 4 independent column FMAs
  #define TERM(i) do {                                                       \
    const float wr_ = __uint_as_float(dmov<DPP_ROR(i)>(wb_));                \
    p0_ = fmaf(wr_, eth[0][i], p0_);                                         \
    p1_ = fmaf(wr_, eth[1][i], p1_);                                         \
    p2_ = fmaf(wr_, eth[2][i], p2_);                                         \
    p3_ = fmaf(wr_, eth[3][i], p3_);                                         \
  } while (0)

  auto step = [&](int s, int slot) {
    const float ex_cur = exq;  // exp(em_s - 0.5), computed last step
    int spre = s + 8;
    if (spre > SEQ - 1) spre = SEQ - 1;
    const float em_next = embuf[(s + 1) & 7];  // row s+1 (different slot)
    embuf[slot] = emb[(size_t)spre * NT + j];  // async prefetch, never drained
    exq = __expf(em_next - 0.5f);              // for next step (off-chain)

    // emission multiplier with previous step's renorm folded in (off-chain)
    const float mm = ex_cur * rr;
    Crn -= lgrr;  // account for the fold we just applied

    // ---- fused gather+MAC: 4 column partials over own row-of-16 ----
    const unsigned wb_ = __float_as_uint(nb);
    float p0_ = nb * eth[0][0];
    float p1_ = nb * eth[1][0];
    float p2_ = nb * eth[2][0];
    float p3_ = nb * eth[3][0];
    TERM(1);  TERM(2);  TERM(3);  TERM(4);  TERM(5);
    TERM(6);  TERM(7);  TERM(8);  TERM(9);  TERM(10);
    TERM(11); TERM(12); TERM(13); TERM(14); TERM(15);

    // cross-row/half reduce (verified r3/r6 pattern)
    const float r1 = xchg16(p1_, use0_16);  // col j over row(j^16)'s values
    const float r3 = xchg16(p3_, use0_16);  // col j^32 over row(j^16)'s values
    p0_ += r1;                              // col j over own 32-half
    p2_ += r3;                              // col j^32 over own 32-half
    const float r2 = xchg32(p2_, use0_32);  // col j over the other 32-half
    p0_ += r2;                              // full 64-sum

    nb = p0_ * mm;

    // prepare next step's renorm; consumer is the FINAL multiply of the next
    // step, so this chain has a full MAC phase of slack
    const float rv = rlf(nb, 0);
    rr = __builtin_amdgcn_rcpf(rv);
    lgrr = __logf(rr);
  };

  // block 0: steps 1..63
  #pragma unroll 8
  for (int r = 1; r < NT; ++r) step(r, r & 7);

  for (int tb = 1; tb < SEQ / NT; ++tb) {
    tagv = tgb[tb * NT + j];
    int ptag = __shfl_up(tagv, 1);
    if (j == 0) ptag = carry;
    scp += sT[ptag * NT + tagv];
    const int base = tb * NT;
    scp += emb[(size_t)(base + j) * NT + tagv];  // em[s][tag_s] gather, own tag
    carry = __builtin_amdgcn_readlane(tagv, 63);

    #pragma unroll 8
    for (int r = 0; r < NT; ++r) step(base + r, r & 7);
  }

  // ---- epilogue ----
  const float endv = endT[j];
  const float x = nb * __expf(endv);
  const float tot = bsum(x);
  // per-step constant: log64 (ET scale) + 0.5 (em shift), applied SEQ-1 times
  const float Cbase = c0 + (float)(SEQ - 1) * (0.5f + 4.1588830833596715f);
  const float logz = Cbase + Crn + __logf(tot);

  const float sctot = bsum(scp);
  const float score = sc0 + sctot + rlf(endv, carry);

  if (j == 0) ws[b] = logz - score;
}

__global__ __launch_bounds__(64) void reduce_loss(const float* __restrict__ ws,
                                                  float* __restrict__ out) {
  const int t = threadIdx.x;
  float v = 0.f;
  #pragma unroll
  for (int k = 0; k < BATCH / 64; ++k) v += ws[k * 64 + t];
  const float tot = bsum(v);
  if (t == 0) out[0] = tot;
}

extern "C" void kernel_launch(void* const* d_in, const int* in_sizes, int n_in,
                              void* d_out, int out_size, void* d_ws, size_t ws_size,
                              hipStream_t stream) {
  const float* em    = (const float*)d_in[0];
  const float* st    = (const float*)d_in[1];
  const float* en    = (const float*)d_in[2];
  const float* tr    = (const float*)d_in[3];
  const int*   tags  = (const int*)d_in[4];
  // d_in[5] is mask: all-ones by construction -> ignored.

  float* ws  = (float*)d_ws;
  float* out = (float*)d_out;

  crf_fwd<<<BATCH, 64, 0, stream>>>(em, st, en, tr, tags, ws);
  reduce_loss<<<1, 64, 0, stream>>>(ws, out);
}